// Round 1
// baseline (5029.247 us; speedup 1.0000x reference)
//
#include <hip/hip_runtime.h>
#include <hip/hip_bf16.h>

// Problem constants (B, L, D, H from reference)
constexpr int kB  = 2;
constexpr int kL  = 2048;
constexpr int kD  = 1024;
constexpr int kH  = 16;
constexpr int kDH = 64;           // head dim
constexpr int kM  = kB * kL;      // GEMM rows = 4096

// ---------------------------------------------------------------------------
// Kernel 1: causal attention, one wave (64 lanes) per query row.
// Lane d holds q_d (d in [0,64)). For each key j<=qi:
//   coalesced load of K[j][:] (lane d reads element d), shfl-reduce dot,
//   online softmax update, coalesced V[j][:] accumulate.
// Output A is written in merged-head layout [B, L, D] (head h -> cols h*64..).
// ---------------------------------------------------------------------------
__global__ __launch_bounds__(256) void attn_kernel(const float* __restrict__ Q,
                                                   const float* __restrict__ K,
                                                   const float* __restrict__ V,
                                                   float* __restrict__ A) {
    const int lane = threadIdx.x & 63;
    const int wave = threadIdx.x >> 6;
    const int tilesPerBH = kL / 4;
    const int bh   = blockIdx.x / tilesPerBH;
    const int tile = blockIdx.x % tilesPerBH;
    const int b = bh / kH;
    const int h = bh % kH;
    const int qi = tile * 4 + wave;

    const size_t base = (size_t)b * kL * kD + (size_t)h * kDH;
    const float* kptr = K + base;
    const float* vptr = V + base;

    // pre-scale q by 1/sqrt(dh) = 1/8
    const float qd = Q[base + (size_t)qi * kD + lane] * 0.125f;

    float m = -3.0e38f;
    float l = 0.0f;
    float acc = 0.0f;

    for (int j = 0; j <= qi; ++j) {
        const float kd = kptr[(size_t)j * kD + lane];
        float s = qd * kd;
        #pragma unroll
        for (int off = 32; off; off >>= 1) s += __shfl_xor(s, off);

        const float mnew = fmaxf(m, s);
        const float corr = __expf(m - mnew);   // first iter: exp(-inf) = 0
        const float p    = __expf(s - mnew);
        const float vd   = vptr[(size_t)j * kD + lane];
        l   = l * corr + p;
        acc = acc * corr + p * vd;
        m = mnew;
    }

    A[base + (size_t)qi * kD + lane] = acc / l;
}

// ---------------------------------------------------------------------------
// Kernel 2: out[M=4096, N=1024] = A[M, K=1024] @ W[K, N] + bias[N]
// 64x64 tile per 256-thread block, 4x4 outputs/thread, BK=16 LDS staging.
// ---------------------------------------------------------------------------
__global__ __launch_bounds__(256) void proj_kernel(const float* __restrict__ A,
                                                   const float* __restrict__ W,
                                                   const float* __restrict__ bias,
                                                   float* __restrict__ out) {
    __shared__ __align__(16) float As[16][64];   // [k][m]
    __shared__ __align__(16) float Ws[16][64];   // [k][n]

    const int t  = threadIdx.x;
    const int m0 = blockIdx.x * 64;   // 64 blocks
    const int n0 = blockIdx.y * 64;   // 16 blocks
    const int tx = t & 15;            // n-group
    const int ty = t >> 4;            // m-group

    // staging indices
    const int arow  = t >> 2;         // 0..63
    const int acol4 = (t & 3) * 4;    // 0,4,8,12
    const int wrow  = t >> 4;         // 0..15
    const int wcol4 = (t & 15) * 4;   // 0..60

    float c[4][4] = {};

    for (int k0 = 0; k0 < kD; k0 += 16) {
        const float4 av = *(const float4*)(A + (size_t)(m0 + arow) * kD + k0 + acol4);
        const float4 wv = *(const float4*)(W + (size_t)(k0 + wrow) * kD + n0 + wcol4);
        __syncthreads();
        As[acol4 + 0][arow] = av.x;
        As[acol4 + 1][arow] = av.y;
        As[acol4 + 2][arow] = av.z;
        As[acol4 + 3][arow] = av.w;
        *(float4*)&Ws[wrow][wcol4] = wv;
        __syncthreads();

        #pragma unroll
        for (int kk = 0; kk < 16; ++kk) {
            const float4 a = *(const float4*)&As[kk][ty * 4];
            const float4 w = *(const float4*)&Ws[kk][tx * 4];
            c[0][0] += a.x * w.x; c[0][1] += a.x * w.y; c[0][2] += a.x * w.z; c[0][3] += a.x * w.w;
            c[1][0] += a.y * w.x; c[1][1] += a.y * w.y; c[1][2] += a.y * w.z; c[1][3] += a.y * w.w;
            c[2][0] += a.z * w.x; c[2][1] += a.z * w.y; c[2][2] += a.z * w.z; c[2][3] += a.z * w.w;
            c[3][0] += a.w * w.x; c[3][1] += a.w * w.y; c[3][2] += a.w * w.z; c[3][3] += a.w * w.w;
        }
    }

    const float4 bv = *(const float4*)(bias + n0 + tx * 4);
    #pragma unroll
    for (int i = 0; i < 4; ++i) {
        float4 o;
        o.x = c[i][0] + bv.x;
        o.y = c[i][1] + bv.y;
        o.z = c[i][2] + bv.z;
        o.w = c[i][3] + bv.w;
        *(float4*)(out + (size_t)(m0 + ty * 4 + i) * kD + n0 + tx * 4) = o;
    }
}

extern "C" void kernel_launch(void* const* d_in, const int* in_sizes, int n_in,
                              void* d_out, int out_size, void* d_ws, size_t ws_size,
                              hipStream_t stream) {
    const float* Q    = (const float*)d_in[0];
    const float* K    = (const float*)d_in[1];
    const float* V    = (const float*)d_in[2];
    const float* W    = (const float*)d_in[3];
    const float* bias = (const float*)d_in[4];
    float* out = (float*)d_out;
    float* A   = (float*)d_ws;   // [B, L, D] merged-head attention output, 16 MB

    attn_kernel<<<dim3(kB * kH * (kL / 4)), 256, 0, stream>>>(Q, K, V, A);
    proj_kernel<<<dim3(kM / 64, kD / 64), 256, 0, stream>>>(A, W, bias, out);
}

// Round 2
// 241.291 us; speedup vs baseline: 20.8430x; 20.8430x over previous
//
#include <hip/hip_runtime.h>
#include <hip/hip_bf16.h>

// Problem constants (B, L, D, H from reference)
constexpr int kB  = 2;
constexpr int kL  = 2048;
constexpr int kD  = 1024;
constexpr int kH  = 16;
constexpr int kDH = 64;           // head dim
constexpr int kM  = kB * kL;      // GEMM rows = 4096

typedef _Float16 half8 __attribute__((ext_vector_type(8)));
typedef float    f32x4 __attribute__((ext_vector_type(4)));

// ---------------- workspace layout (bytes) ----------------
constexpr size_t kKhOff = 0;                       // K in f16, [B,L,D]          8.39 MB
constexpr size_t kVtOff = 8388608;                 // V in f16, [B,H,dh,L]       8.39 MB
constexpr size_t kAhOff = 16777216;                // attn out f16, [B,L,D]      8.39 MB
constexpr size_t kWtOff = 25165824;                // W^T in f16, [N,K]          2.10 MB
constexpr size_t kWsNeed = 27262976;

// ===========================================================================
// fp32 -> f16 elementwise (for K). One thread = 8 elements.
// ===========================================================================
__global__ void conv_half(const float* __restrict__ src, _Float16* __restrict__ dst) {
    size_t i = ((size_t)blockIdx.x * 256 + threadIdx.x) * 8;
    float4 f0 = *(const float4*)(src + i);
    float4 f1 = *(const float4*)(src + i + 4);
    half8 h;
    h[0] = (_Float16)f0.x; h[1] = (_Float16)f0.y; h[2] = (_Float16)f0.z; h[3] = (_Float16)f0.w;
    h[4] = (_Float16)f1.x; h[5] = (_Float16)f1.y; h[6] = (_Float16)f1.z; h[7] = (_Float16)f1.w;
    *(half8*)(dst + i) = h;
}

// ===========================================================================
// V [B,L,D] fp32 -> Vt [B,H,dh,L] f16   (per-head transpose, LDS staged)
// grid: B*H*(L/64) blocks; block handles 64 l x 64 ch of one (b,h).
// ===========================================================================
__global__ __launch_bounds__(256) void conv_vt(const float* __restrict__ V,
                                               _Float16* __restrict__ Vt) {
    __shared__ _Float16 Ts[64][65];
    const int t = threadIdx.x;
    const int bid = blockIdx.x;
    const int lt = bid & 31, h = (bid >> 5) & 15, b = bid >> 9;
    for (int p = 0; p < 16; ++p) {
        int i = p * 256 + t;
        int r = i >> 6, c = i & 63;                // r = l-row, c = channel
        Ts[r][c] = (_Float16)V[((size_t)(b * kL + lt * 64 + r)) * kD + h * kDH + c];
    }
    __syncthreads();
    for (int p = 0; p < 16; ++p) {
        int i = p * 256 + t;
        int r = i >> 6, c = i & 63;                // r = channel, c = l-col
        Vt[((size_t)(b * kH + h) * kDH + r) * kL + lt * 64 + c] = Ts[c][r];
    }
}

// ===========================================================================
// W [K,N] fp32 -> Wt [N,K] f16
// ===========================================================================
__global__ __launch_bounds__(256) void conv_wt(const float* __restrict__ W,
                                               _Float16* __restrict__ Wt) {
    __shared__ _Float16 Ts[64][65];
    const int t = threadIdx.x;
    const int nt = blockIdx.x & 15, kt = blockIdx.x >> 4;
    const int k0 = kt * 64, n0 = nt * 64;
    for (int p = 0; p < 16; ++p) {
        int i = p * 256 + t;
        int r = i >> 6, c = i & 63;                // r = k-row, c = n
        Ts[r][c] = (_Float16)W[(size_t)(k0 + r) * kD + n0 + c];
    }
    __syncthreads();
    for (int p = 0; p < 16; ++p) {
        int i = p * 256 + t;
        int r = i >> 6, c = i & 63;                // r = n, c = k
        Wt[(size_t)(n0 + r) * kD + k0 + c] = Ts[c][r];
    }
}

// ===========================================================================
// Flash attention, f16 MFMA 16x16x32. Block = 64 queries of one (b,h),
// 4 waves x 16 query rows. Causal: iterate key tiles 0..qt, mask diagonal.
// A-frag: A[m=lane&15][k=quad*8+j]; B-frag: B[k=quad*8+j][n=lane&15];
// C/D: row=quad*4+reg, col=lane&15  (per m89/m118/m120).
// ===========================================================================
__global__ __launch_bounds__(256) void flash_kernel(const float* __restrict__ Q,
                                                    const _Float16* __restrict__ Kh,
                                                    const _Float16* __restrict__ Vt,
                                                    _Float16* __restrict__ Ah) {
    constexpr int PAD = 72;                        // 64 + 8: keeps <=2-way LDS conflicts
    __shared__ __align__(16) _Float16 Ks[64 * PAD];   // [key][ch]
    __shared__ __align__(16) _Float16 Vs[64 * PAD];   // [ch][key]  (from Vt)
    __shared__ __align__(16) _Float16 Ps[4][16 * PAD]; // per-wave P tile [row][key]

    const int t = threadIdx.x;
    const int lane = t & 63, w = t >> 6;
    const int l15 = lane & 15, quad = lane >> 4;
    const int bid = blockIdx.x;
    const int qt = bid & 31, h = (bid >> 5) & 15, b = bid >> 9;

    // --- Q fragments (load fp32, scale by 1/8, convert) ---
    const size_t qrow = (size_t)(b * kL + qt * 64 + w * 16 + l15);
    const float* qp = Q + qrow * kD + h * kDH + quad * 8;
    half8 aq[2];
    #pragma unroll
    for (int kc = 0; kc < 2; ++kc) {
        float4 f0 = *(const float4*)(qp + kc * 32);
        float4 f1 = *(const float4*)(qp + kc * 32 + 4);
        aq[kc][0] = (_Float16)(f0.x * 0.125f); aq[kc][1] = (_Float16)(f0.y * 0.125f);
        aq[kc][2] = (_Float16)(f0.z * 0.125f); aq[kc][3] = (_Float16)(f0.w * 0.125f);
        aq[kc][4] = (_Float16)(f1.x * 0.125f); aq[kc][5] = (_Float16)(f1.y * 0.125f);
        aq[kc][6] = (_Float16)(f1.z * 0.125f); aq[kc][7] = (_Float16)(f1.w * 0.125f);
    }

    f32x4 o[4];
    float mst[4], lst[4];
    #pragma unroll
    for (int r = 0; r < 4; ++r) { o[r] = (f32x4){0.f, 0.f, 0.f, 0.f}; mst[r] = -3.0e38f; lst[r] = 0.f; }

    const _Float16* kbase = Kh + (size_t)(b * kL) * kD + h * kDH;
    const _Float16* vbase = Vt + (size_t)(b * kH + h) * kDH * kL;

    for (int kt = 0; kt <= qt; ++kt) {
        __syncthreads();
        // ---- stage K tile [64 key][64 ch] and V tile [64 ch][64 key] ----
        #pragma unroll
        for (int p = 0; p < 2; ++p) {
            int idx = p * 256 + t;
            int row = idx >> 3, seg = idx & 7;
            *(float4*)&Ks[row * PAD + seg * 8] =
                *(const float4*)(kbase + (size_t)(kt * 64 + row) * kD + seg * 8);
            *(float4*)&Vs[row * PAD + seg * 8] =
                *(const float4*)(vbase + (size_t)row * kL + kt * 64 + seg * 8);
        }
        __syncthreads();

        // ---- S = Q K^T : 4 n-tiles (keys) x 2 k-chunks ----
        f32x4 s[4];
        #pragma unroll
        for (int nt = 0; nt < 4; ++nt) {
            s[nt] = (f32x4){0.f, 0.f, 0.f, 0.f};
            #pragma unroll
            for (int kc = 0; kc < 2; ++kc) {
                half8 bk = *(half8*)&Ks[(nt * 16 + l15) * PAD + kc * 32 + quad * 8];
                s[nt] = __builtin_amdgcn_mfma_f32_16x16x32_f16(aq[kc], bk, s[nt], 0, 0, 0);
            }
        }

        // ---- diagonal mask ----
        if (kt == qt) {
            #pragma unroll
            for (int nt = 0; nt < 4; ++nt)
                #pragma unroll
                for (int r = 0; r < 4; ++r)
                    if (nt * 16 + l15 > w * 16 + quad * 4 + r) s[nt][r] = -1.0e30f;
        }

        // ---- row max (across 4 n-tiles, then across the quad's 16 lanes) ----
        float mx[4];
        #pragma unroll
        for (int r = 0; r < 4; ++r)
            mx[r] = fmaxf(fmaxf(s[0][r], s[1][r]), fmaxf(s[2][r], s[3][r]));
        #pragma unroll
        for (int off = 1; off < 16; off <<= 1)
            #pragma unroll
            for (int r = 0; r < 4; ++r)
                mx[r] = fmaxf(mx[r], __shfl_xor(mx[r], off));

        // ---- online softmax update ----
        float corr[4], rs[4];
        #pragma unroll
        for (int r = 0; r < 4; ++r) {
            float mnew = fmaxf(mst[r], mx[r]);
            corr[r] = __expf(mst[r] - mnew);      // first tile: expf(-huge) = 0
            mst[r] = mnew;
            rs[r] = 0.f;
        }
        #pragma unroll
        for (int nt = 0; nt < 4; ++nt)
            #pragma unroll
            for (int r = 0; r < 4; ++r) {
                float p = __expf(s[nt][r] - mst[r]);
                s[nt][r] = p;
                rs[r] += p;
            }
        #pragma unroll
        for (int off = 1; off < 16; off <<= 1)
            #pragma unroll
            for (int r = 0; r < 4; ++r)
                rs[r] += __shfl_xor(rs[r], off);
        #pragma unroll
        for (int r = 0; r < 4; ++r) lst[r] = lst[r] * corr[r] + rs[r];

        // ---- P: C-layout -> LDS -> A-layout (wave-private region) ----
        #pragma unroll
        for (int nt = 0; nt < 4; ++nt)
            #pragma unroll
            for (int r = 0; r < 4; ++r)
                Ps[w][(quad * 4 + r) * PAD + nt * 16 + l15] = (_Float16)s[nt][r];

        // ---- rescale O ----
        #pragma unroll
        for (int nt = 0; nt < 4; ++nt)
            #pragma unroll
            for (int r = 0; r < 4; ++r)
                o[nt][r] *= corr[r];

        // ---- O += P V : 4 n-tiles (channels) x 2 k-chunks (keys) ----
        half8 ap[2];
        #pragma unroll
        for (int kc = 0; kc < 2; ++kc)
            ap[kc] = *(half8*)&Ps[w][l15 * PAD + kc * 32 + quad * 8];
        #pragma unroll
        for (int nt = 0; nt < 4; ++nt)
            #pragma unroll
            for (int kc = 0; kc < 2; ++kc) {
                half8 bv = *(half8*)&Vs[(nt * 16 + l15) * PAD + kc * 32 + quad * 8];
                o[nt] = __builtin_amdgcn_mfma_f32_16x16x32_f16(ap[kc], bv, o[nt], 0, 0, 0);
            }
    }

    // ---- epilogue: normalize, write f16 merged-head A ----
    const size_t orow = (size_t)(b * kL + qt * 64 + w * 16 + quad * 4);
    #pragma unroll
    for (int r = 0; r < 4; ++r) {
        float inv = 1.0f / lst[r];
        #pragma unroll
        for (int nt = 0; nt < 4; ++nt)
            Ah[(orow + r) * kD + h * kDH + nt * 16 + l15] = (_Float16)(o[nt][r] * inv);
    }
}

// ===========================================================================
// Projection: out[4096,1024] = Ah[4096,1024] @ Wt^T + bias, f16 MFMA.
// 64x64 tile/block, 4 waves each 32x32 (2x2 fragments), BK=64.
// ===========================================================================
__global__ __launch_bounds__(256) void proj_half(const _Float16* __restrict__ Ah,
                                                 const _Float16* __restrict__ Wt,
                                                 const float* __restrict__ bias,
                                                 float* __restrict__ out) {
    constexpr int PAD = 72;
    __shared__ __align__(16) _Float16 As[64 * PAD];   // [m][k]
    __shared__ __align__(16) _Float16 Bs[64 * PAD];   // [n][k]

    const int t = threadIdx.x;
    const int lane = t & 63, w = t >> 6;
    const int l15 = lane & 15, quad = lane >> 4;
    const int m0 = blockIdx.x * 64, n0 = blockIdx.y * 64;
    const int wm = (w >> 1) * 32, wn = (w & 1) * 32;

    f32x4 c[2][2];
    #pragma unroll
    for (int i = 0; i < 2; ++i)
        #pragma unroll
        for (int j = 0; j < 2; ++j) c[i][j] = (f32x4){0.f, 0.f, 0.f, 0.f};

    for (int k0 = 0; k0 < kD; k0 += 64) {
        __syncthreads();
        #pragma unroll
        for (int p = 0; p < 2; ++p) {
            int idx = p * 256 + t;
            int row = idx >> 3, seg = idx & 7;
            *(float4*)&As[row * PAD + seg * 8] =
                *(const float4*)(Ah + (size_t)(m0 + row) * kD + k0 + seg * 8);
            *(float4*)&Bs[row * PAD + seg * 8] =
                *(const float4*)(Wt + (size_t)(n0 + row) * kD + k0 + seg * 8);
        }
        __syncthreads();

        #pragma unroll
        for (int kc = 0; kc < 2; ++kc) {
            half8 a0 = *(half8*)&As[(wm + l15) * PAD + kc * 32 + quad * 8];
            half8 a1 = *(half8*)&As[(wm + 16 + l15) * PAD + kc * 32 + quad * 8];
            half8 b0 = *(half8*)&Bs[(wn + l15) * PAD + kc * 32 + quad * 8];
            half8 b1 = *(half8*)&Bs[(wn + 16 + l15) * PAD + kc * 32 + quad * 8];
            c[0][0] = __builtin_amdgcn_mfma_f32_16x16x32_f16(a0, b0, c[0][0], 0, 0, 0);
            c[0][1] = __builtin_amdgcn_mfma_f32_16x16x32_f16(a0, b1, c[0][1], 0, 0, 0);
            c[1][0] = __builtin_amdgcn_mfma_f32_16x16x32_f16(a1, b0, c[1][0], 0, 0, 0);
            c[1][1] = __builtin_amdgcn_mfma_f32_16x16x32_f16(a1, b1, c[1][1], 0, 0, 0);
        }
    }

    #pragma unroll
    for (int bn = 0; bn < 2; ++bn) {
        int n = n0 + wn + bn * 16 + l15;
        float bv = bias[n];
        #pragma unroll
        for (int am = 0; am < 2; ++am) {
            int mrow = m0 + wm + am * 16 + quad * 4;
            #pragma unroll
            for (int r = 0; r < 4; ++r)
                out[(size_t)(mrow + r) * kD + n] = c[am][bn][r] + bv;
        }
    }
}

// ===========================================================================
// Fallback fp32 path (round-1 kernels) in case d_ws is too small.
// ===========================================================================
__global__ __launch_bounds__(256) void attn_kernel_f32(const float* __restrict__ Q,
                                                       const float* __restrict__ K,
                                                       const float* __restrict__ V,
                                                       float* __restrict__ A) {
    const int lane = threadIdx.x & 63;
    const int wave = threadIdx.x >> 6;
    const int tilesPerBH = kL / 4;
    const int bh = blockIdx.x / tilesPerBH;
    const int tile = blockIdx.x % tilesPerBH;
    const int b = bh / kH, h = bh % kH;
    const int qi = tile * 4 + wave;
    const size_t base = (size_t)b * kL * kD + (size_t)h * kDH;
    const float* kptr = K + base;
    const float* vptr = V + base;
    const float qd = Q[base + (size_t)qi * kD + lane] * 0.125f;
    float m = -3.0e38f, l = 0.0f, acc = 0.0f;
    for (int j = 0; j <= qi; ++j) {
        const float kd = kptr[(size_t)j * kD + lane];
        float s = qd * kd;
        #pragma unroll
        for (int off = 32; off; off >>= 1) s += __shfl_xor(s, off);
        const float mnew = fmaxf(m, s);
        const float corr = __expf(m - mnew);
        const float p = __expf(s - mnew);
        const float vd = vptr[(size_t)j * kD + lane];
        l = l * corr + p;
        acc = acc * corr + p * vd;
        m = mnew;
    }
    A[base + (size_t)qi * kD + lane] = acc / l;
}

__global__ __launch_bounds__(256) void proj_kernel_f32(const float* __restrict__ A,
                                                       const float* __restrict__ W,
                                                       const float* __restrict__ bias,
                                                       float* __restrict__ out) {
    __shared__ __align__(16) float As[16][64];
    __shared__ __align__(16) float Ws[16][64];
    const int t = threadIdx.x;
    const int m0 = blockIdx.x * 64, n0 = blockIdx.y * 64;
    const int tx = t & 15, ty = t >> 4;
    const int arow = t >> 2, acol4 = (t & 3) * 4;
    const int wrow = t >> 4, wcol4 = (t & 15) * 4;
    float c[4][4] = {};
    for (int k0 = 0; k0 < kD; k0 += 16) {
        const float4 av = *(const float4*)(A + (size_t)(m0 + arow) * kD + k0 + acol4);
        const float4 wv = *(const float4*)(W + (size_t)(k0 + wrow) * kD + n0 + wcol4);
        __syncthreads();
        As[acol4 + 0][arow] = av.x;
        As[acol4 + 1][arow] = av.y;
        As[acol4 + 2][arow] = av.z;
        As[acol4 + 3][arow] = av.w;
        *(float4*)&Ws[wrow][wcol4] = wv;
        __syncthreads();
        #pragma unroll
        for (int kk = 0; kk < 16; ++kk) {
            const float4 a = *(const float4*)&As[kk][ty * 4];
            const float4 wv2 = *(const float4*)&Ws[kk][tx * 4];
            c[0][0] += a.x * wv2.x; c[0][1] += a.x * wv2.y; c[0][2] += a.x * wv2.z; c[0][3] += a.x * wv2.w;
            c[1][0] += a.y * wv2.x; c[1][1] += a.y * wv2.y; c[1][2] += a.y * wv2.z; c[1][3] += a.y * wv2.w;
            c[2][0] += a.z * wv2.x; c[2][1] += a.z * wv2.y; c[2][2] += a.z * wv2.z; c[2][3] += a.z * wv2.w;
            c[3][0] += a.w * wv2.x; c[3][1] += a.w * wv2.y; c[3][2] += a.w * wv2.z; c[3][3] += a.w * wv2.w;
        }
    }
    const float4 bv = *(const float4*)(bias + n0 + tx * 4);
    #pragma unroll
    for (int i = 0; i < 4; ++i) {
        float4 o;
        o.x = c[i][0] + bv.x; o.y = c[i][1] + bv.y; o.z = c[i][2] + bv.z; o.w = c[i][3] + bv.w;
        *(float4*)(out + (size_t)(m0 + ty * 4 + i) * kD + n0 + tx * 4) = o;
    }
}

extern "C" void kernel_launch(void* const* d_in, const int* in_sizes, int n_in,
                              void* d_out, int out_size, void* d_ws, size_t ws_size,
                              hipStream_t stream) {
    const float* Q    = (const float*)d_in[0];
    const float* K    = (const float*)d_in[1];
    const float* V    = (const float*)d_in[2];
    const float* W    = (const float*)d_in[3];
    const float* bias = (const float*)d_in[4];
    float* out = (float*)d_out;

    if (ws_size >= kWsNeed) {
        char* ws = (char*)d_ws;
        _Float16* Kh = (_Float16*)(ws + kKhOff);
        _Float16* Vt = (_Float16*)(ws + kVtOff);
        _Float16* Ah = (_Float16*)(ws + kAhOff);
        _Float16* Wt = (_Float16*)(ws + kWtOff);

        conv_half<<<dim3((kB * kL * kD) / (256 * 8)), 256, 0, stream>>>(K, Kh);
        conv_vt<<<dim3(kB * kH * (kL / 64)), 256, 0, stream>>>(V, Vt);
        conv_wt<<<dim3(256), 256, 0, stream>>>(W, Wt);
        flash_kernel<<<dim3(kB * kH * (kL / 64)), 256, 0, stream>>>(Q, Kh, Vt, Ah);
        proj_half<<<dim3(kM / 64, kD / 64), 256, 0, stream>>>(Ah, Wt, bias, out);
    } else {
        float* A = (float*)d_ws;
        attn_kernel_f32<<<dim3(kB * kH * (kL / 4)), 256, 0, stream>>>(Q, K, V, A);
        proj_kernel_f32<<<dim3(kM / 64, kD / 64), 256, 0, stream>>>(A, W, bias, out);
    }
}

// Round 3
// 218.348 us; speedup vs baseline: 23.0331x; 1.1051x over previous
//
#include <hip/hip_runtime.h>
#include <hip/hip_bf16.h>

// Problem constants (B, L, D, H from reference)
constexpr int kB  = 2;
constexpr int kL  = 2048;
constexpr int kD  = 1024;
constexpr int kH  = 16;
constexpr int kDH = 64;           // head dim
constexpr int kM  = kB * kL;      // GEMM rows = 4096

typedef _Float16 half8 __attribute__((ext_vector_type(8)));
typedef float    f32x4 __attribute__((ext_vector_type(4)));

// ---------------- workspace layout (bytes) ----------------
constexpr size_t kKhOff = 0;                       // K in f16, [B,L,D]          8.39 MB
constexpr size_t kVtOff = 8388608;                 // V in f16, [B,H,dh,L]       8.39 MB
constexpr size_t kAhOff = 16777216;                // attn out f16, [B,L,D]      8.39 MB
constexpr size_t kWtOff = 25165824;                // W^T in f16, [N,K]          2.10 MB
constexpr size_t kWsNeed = 27262976;

// ===========================================================================
// fp32 -> f16 elementwise (for K). One thread = 8 elements.
// ===========================================================================
__global__ void conv_half(const float* __restrict__ src, _Float16* __restrict__ dst) {
    size_t i = ((size_t)blockIdx.x * 256 + threadIdx.x) * 8;
    float4 f0 = *(const float4*)(src + i);
    float4 f1 = *(const float4*)(src + i + 4);
    half8 h;
    h[0] = (_Float16)f0.x; h[1] = (_Float16)f0.y; h[2] = (_Float16)f0.z; h[3] = (_Float16)f0.w;
    h[4] = (_Float16)f1.x; h[5] = (_Float16)f1.y; h[6] = (_Float16)f1.z; h[7] = (_Float16)f1.w;
    *(half8*)(dst + i) = h;
}

// ===========================================================================
// V [B,L,D] fp32 -> Vt [B,H,dh,L] f16   (per-head transpose, LDS staged)
// ===========================================================================
__global__ __launch_bounds__(256) void conv_vt(const float* __restrict__ V,
                                               _Float16* __restrict__ Vt) {
    __shared__ _Float16 Ts[64][65];
    const int t = threadIdx.x;
    const int bid = blockIdx.x;
    const int lt = bid & 31, h = (bid >> 5) & 15, b = bid >> 9;
    for (int p = 0; p < 16; ++p) {
        int i = p * 256 + t;
        int r = i >> 6, c = i & 63;                // r = l-row, c = channel
        Ts[r][c] = (_Float16)V[((size_t)(b * kL + lt * 64 + r)) * kD + h * kDH + c];
    }
    __syncthreads();
    for (int p = 0; p < 16; ++p) {
        int i = p * 256 + t;
        int r = i >> 6, c = i & 63;                // r = channel, c = l-col
        Vt[((size_t)(b * kH + h) * kDH + r) * kL + lt * 64 + c] = Ts[c][r];
    }
}

// ===========================================================================
// W [K,N] fp32 -> Wt [N,K] f16
// ===========================================================================
__global__ __launch_bounds__(256) void conv_wt(const float* __restrict__ W,
                                               _Float16* __restrict__ Wt) {
    __shared__ _Float16 Ts[64][65];
    const int t = threadIdx.x;
    const int nt = blockIdx.x & 15, kt = blockIdx.x >> 4;
    const int k0 = kt * 64, n0 = nt * 64;
    for (int p = 0; p < 16; ++p) {
        int i = p * 256 + t;
        int r = i >> 6, c = i & 63;                // r = k-row, c = n
        Ts[r][c] = (_Float16)W[(size_t)(k0 + r) * kD + n0 + c];
    }
    __syncthreads();
    for (int p = 0; p < 16; ++p) {
        int i = p * 256 + t;
        int r = i >> 6, c = i & 63;                // r = n, c = k
        Wt[(size_t)(n0 + r) * kD + k0 + c] = Ts[c][r];
    }
}

// ===========================================================================
// Barrier-free flash attention. One wave owns 32 query rows (2 m-tiles of 16).
// K/V MFMA B-fragments are loaded DIRECTLY global->VGPR (contiguous half8
// thanks to Kh [L,D] and Vt [bh,ch,L] layouts) -- no LDS staging, no
// __syncthreads. P transposes through wave-private LDS (m120 transform).
// Waves of a block cover 4 consecutive 32-row tiles -> near-equal work;
// blocks launched longest-first (g descending) for makespan.
// Layouts (verified in round 2): A[m=l15][k=quad*8+j]; B[k=quad*8+j][n=l15];
// C/D row=quad*4+reg, col=l15.
// ===========================================================================
__global__ __launch_bounds__(256, 2) void flash_kernel(const float* __restrict__ Q,
                                                       const _Float16* __restrict__ Kh,
                                                       const _Float16* __restrict__ Vt,
                                                       _Float16* __restrict__ Ah) {
    constexpr int PADP = 72;                       // half8-aligned rows; 2-way-bank (free)
    __shared__ __align__(16) _Float16 Ps[8][16 * PADP];  // [wave*2+mt][row][key]

    const int t = threadIdx.x;
    const int lane = t & 63, w = t >> 6;
    const int l15 = lane & 15, quad = lane >> 4;
    const int bid = blockIdx.x;
    const int bh = bid & 31;
    const int g  = 15 - (bid >> 5);                // longest blocks dispatched first
    const int b = bh >> 4, h = bh & 15;
    const int qw = g * 4 + w;                      // this wave's 32-row tile index
    const int qbase = qw << 5;
    const int Tq = (qw >> 1) + 1;                  // number of 64-key tiles

    const size_t hoff = (size_t)h * kDH;

    // --- Q fragments: fp32 load, scale 1/8, convert. aq[mt][kc] ---
    half8 aq[2][2];
    #pragma unroll
    for (int mt = 0; mt < 2; ++mt)
        #pragma unroll
        for (int kc = 0; kc < 2; ++kc) {
            const float* qp = Q + (size_t)(b * kL + qbase + mt * 16 + l15) * kD
                              + hoff + kc * 32 + quad * 8;
            float4 f0 = *(const float4*)qp;
            float4 f1 = *(const float4*)(qp + 4);
            half8 hq;
            hq[0] = (_Float16)(f0.x * 0.125f); hq[1] = (_Float16)(f0.y * 0.125f);
            hq[2] = (_Float16)(f0.z * 0.125f); hq[3] = (_Float16)(f0.w * 0.125f);
            hq[4] = (_Float16)(f1.x * 0.125f); hq[5] = (_Float16)(f1.y * 0.125f);
            hq[6] = (_Float16)(f1.z * 0.125f); hq[7] = (_Float16)(f1.w * 0.125f);
            aq[mt][kc] = hq;
        }

    f32x4 o[2][4];
    float mst[2][4], lst[2][4];
    #pragma unroll
    for (int mt = 0; mt < 2; ++mt)
        #pragma unroll
        for (int r = 0; r < 4; ++r) {
            o[mt][r & 3] = o[mt][r & 3];           // no-op, keep indices clear
        }
    #pragma unroll
    for (int mt = 0; mt < 2; ++mt) {
        #pragma unroll
        for (int nt = 0; nt < 4; ++nt) o[mt][nt] = (f32x4){0.f, 0.f, 0.f, 0.f};
        #pragma unroll
        for (int r = 0; r < 4; ++r) { mst[mt][r] = -3.0e38f; lst[mt][r] = 0.f; }
    }

    const _Float16* kbp = Kh + (size_t)(b * kL) * kD + hoff;
    const _Float16* vbp = Vt + (size_t)(bh * kDH) * kL;

    for (int kt = 0; kt < Tq; ++kt) {
        const int kb = kt * 64;

        // ---- direct global B-fragment loads (16 x half8, all independent) ----
        half8 bk[4][2], bv[4][2];
        #pragma unroll
        for (int nt = 0; nt < 4; ++nt)
            #pragma unroll
            for (int kc = 0; kc < 2; ++kc)
                bk[nt][kc] = *(const half8*)(kbp + (size_t)(kb + nt * 16 + l15) * kD
                                             + kc * 32 + quad * 8);
        #pragma unroll
        for (int nt = 0; nt < 4; ++nt)
            #pragma unroll
            for (int kc = 0; kc < 2; ++kc)
                bv[nt][kc] = *(const half8*)(vbp + (size_t)(nt * 16 + l15) * kL
                                             + kb + kc * 32 + quad * 8);

        #pragma unroll
        for (int mt = 0; mt < 2; ++mt) {
            // ---- S = Q K^T (16x64) ----
            f32x4 s[4];
            #pragma unroll
            for (int nt = 0; nt < 4; ++nt) {
                s[nt] = (f32x4){0.f, 0.f, 0.f, 0.f};
                #pragma unroll
                for (int kc = 0; kc < 2; ++kc)
                    s[nt] = __builtin_amdgcn_mfma_f32_16x16x32_f16(aq[mt][kc], bk[nt][kc], s[nt], 0, 0, 0);
            }

            // ---- causal mask on the last (diagonal-straddling) tile ----
            if (kt == Tq - 1) {
                const int row = qbase + mt * 16 + quad * 4;
                #pragma unroll
                for (int nt = 0; nt < 4; ++nt)
                    #pragma unroll
                    for (int r = 0; r < 4; ++r)
                        if (kb + nt * 16 + l15 > row + r) s[nt][r] = -1.0e30f;
            }

            // ---- row max across 64 keys ----
            float mx[4];
            #pragma unroll
            for (int r = 0; r < 4; ++r)
                mx[r] = fmaxf(fmaxf(s[0][r], s[1][r]), fmaxf(s[2][r], s[3][r]));
            #pragma unroll
            for (int off = 1; off < 16; off <<= 1)
                #pragma unroll
                for (int r = 0; r < 4; ++r)
                    mx[r] = fmaxf(mx[r], __shfl_xor(mx[r], off));

            // ---- online softmax ----
            float corr[4], rs[4];
            #pragma unroll
            for (int r = 0; r < 4; ++r) {
                float mnew = fmaxf(mst[mt][r], mx[r]);
                corr[r] = __expf(mst[mt][r] - mnew);
                mst[mt][r] = mnew;
                rs[r] = 0.f;
            }
            #pragma unroll
            for (int nt = 0; nt < 4; ++nt)
                #pragma unroll
                for (int r = 0; r < 4; ++r) {
                    float p = __expf(s[nt][r] - mst[mt][r]);
                    s[nt][r] = p;
                    rs[r] += p;
                }
            #pragma unroll
            for (int off = 1; off < 16; off <<= 1)
                #pragma unroll
                for (int r = 0; r < 4; ++r)
                    rs[r] += __shfl_xor(rs[r], off);
            #pragma unroll
            for (int r = 0; r < 4; ++r) lst[mt][r] = lst[mt][r] * corr[r] + rs[r];

            // ---- P: C-layout -> wave-private LDS -> A-layout ----
            _Float16* pp = Ps[w * 2 + mt];
            #pragma unroll
            for (int nt = 0; nt < 4; ++nt)
                #pragma unroll
                for (int r = 0; r < 4; ++r)
                    pp[(quad * 4 + r) * PADP + nt * 16 + l15] = (_Float16)s[nt][r];

            // ---- rescale O ----
            #pragma unroll
            for (int nt = 0; nt < 4; ++nt)
                #pragma unroll
                for (int r = 0; r < 4; ++r)
                    o[mt][nt][r] *= corr[r];

            // ---- O += P V ----
            half8 ap[2];
            #pragma unroll
            for (int kc = 0; kc < 2; ++kc)
                ap[kc] = *(half8*)&pp[l15 * PADP + kc * 32 + quad * 8];
            #pragma unroll
            for (int nt = 0; nt < 4; ++nt)
                #pragma unroll
                for (int kc = 0; kc < 2; ++kc)
                    o[mt][nt] = __builtin_amdgcn_mfma_f32_16x16x32_f16(ap[kc], bv[nt][kc], o[mt][nt], 0, 0, 0);
        }
    }

    // ---- epilogue ----
    #pragma unroll
    for (int mt = 0; mt < 2; ++mt) {
        const size_t orow = (size_t)(b * kL + qbase + mt * 16 + quad * 4);
        #pragma unroll
        for (int r = 0; r < 4; ++r) {
            float inv = 1.0f / lst[mt][r];
            #pragma unroll
            for (int nt = 0; nt < 4; ++nt)
                Ah[(orow + r) * kD + hoff + nt * 16 + l15] = (_Float16)(o[mt][nt][r] * inv);
        }
    }
}

// ===========================================================================
// Projection: out[4096,1024] = Ah @ Wt^T + bias.  128x64 tile, BK=64,
// 4 waves each 64x32 (4x2 fragments). 512 blocks -> 2/CU.
// ===========================================================================
__global__ __launch_bounds__(256, 2) void proj_half(const _Float16* __restrict__ Ah,
                                                    const _Float16* __restrict__ Wt,
                                                    const float* __restrict__ bias,
                                                    float* __restrict__ out) {
    constexpr int PAD = 72;
    __shared__ __align__(16) _Float16 As[128 * PAD];  // [m][k]
    __shared__ __align__(16) _Float16 Bs[64 * PAD];   // [n][k]

    const int t = threadIdx.x;
    const int lane = t & 63, w = t >> 6;
    const int l15 = lane & 15, quad = lane >> 4;
    const int m0 = blockIdx.x * 128, n0 = blockIdx.y * 64;
    const int wm = (w >> 1) * 64, wn = (w & 1) * 32;

    f32x4 c[4][2];
    #pragma unroll
    for (int i = 0; i < 4; ++i)
        #pragma unroll
        for (int j = 0; j < 2; ++j) c[i][j] = (f32x4){0.f, 0.f, 0.f, 0.f};

    for (int k0 = 0; k0 < kD; k0 += 64) {
        __syncthreads();
        #pragma unroll
        for (int p = 0; p < 4; ++p) {
            int idx = p * 256 + t;
            int row = idx >> 3, seg = idx & 7;
            *(half8*)&As[row * PAD + seg * 8] =
                *(const half8*)(Ah + (size_t)(m0 + row) * kD + k0 + seg * 8);
        }
        #pragma unroll
        for (int p = 0; p < 2; ++p) {
            int idx = p * 256 + t;
            int row = idx >> 3, seg = idx & 7;
            *(half8*)&Bs[row * PAD + seg * 8] =
                *(const half8*)(Wt + (size_t)(n0 + row) * kD + k0 + seg * 8);
        }
        __syncthreads();

        #pragma unroll
        for (int kc = 0; kc < 2; ++kc) {
            half8 a[4], bf[2];
            #pragma unroll
            for (int mt = 0; mt < 4; ++mt)
                a[mt] = *(half8*)&As[(wm + mt * 16 + l15) * PAD + kc * 32 + quad * 8];
            #pragma unroll
            for (int nt = 0; nt < 2; ++nt)
                bf[nt] = *(half8*)&Bs[(wn + nt * 16 + l15) * PAD + kc * 32 + quad * 8];
            #pragma unroll
            for (int mt = 0; mt < 4; ++mt)
                #pragma unroll
                for (int nt = 0; nt < 2; ++nt)
                    c[mt][nt] = __builtin_amdgcn_mfma_f32_16x16x32_f16(a[mt], bf[nt], c[mt][nt], 0, 0, 0);
        }
    }

    #pragma unroll
    for (int nt = 0; nt < 2; ++nt) {
        int n = n0 + wn + nt * 16 + l15;
        float bv = bias[n];
        #pragma unroll
        for (int mt = 0; mt < 4; ++mt) {
            int mrow = m0 + wm + mt * 16 + quad * 4;
            #pragma unroll
            for (int r = 0; r < 4; ++r)
                out[(size_t)(mrow + r) * kD + n] = c[mt][nt][r] + bv;
        }
    }
}

// ===========================================================================
// Fallback fp32 path in case d_ws is too small.
// ===========================================================================
__global__ __launch_bounds__(256) void attn_kernel_f32(const float* __restrict__ Q,
                                                       const float* __restrict__ K,
                                                       const float* __restrict__ V,
                                                       float* __restrict__ A) {
    const int lane = threadIdx.x & 63;
    const int wave = threadIdx.x >> 6;
    const int tilesPerBH = kL / 4;
    const int bh = blockIdx.x / tilesPerBH;
    const int tile = blockIdx.x % tilesPerBH;
    const int b = bh / kH, h = bh % kH;
    const int qi = tile * 4 + wave;
    const size_t base = (size_t)b * kL * kD + (size_t)h * kDH;
    const float* kptr = K + base;
    const float* vptr = V + base;
    const float qd = Q[base + (size_t)qi * kD + lane] * 0.125f;
    float m = -3.0e38f, l = 0.0f, acc = 0.0f;
    for (int j = 0; j <= qi; ++j) {
        const float kd = kptr[(size_t)j * kD + lane];
        float s = qd * kd;
        #pragma unroll
        for (int off = 32; off; off >>= 1) s += __shfl_xor(s, off);
        const float mnew = fmaxf(m, s);
        const float corr = __expf(m - mnew);
        const float p = __expf(s - mnew);
        const float vd = vptr[(size_t)j * kD + lane];
        l = l * corr + p;
        acc = acc * corr + p * vd;
        m = mnew;
    }
    A[base + (size_t)qi * kD + lane] = acc / l;
}

__global__ __launch_bounds__(256) void proj_kernel_f32(const float* __restrict__ A,
                                                       const float* __restrict__ W,
                                                       const float* __restrict__ bias,
                                                       float* __restrict__ out) {
    __shared__ __align__(16) float As[16][64];
    __shared__ __align__(16) float Ws[16][64];
    const int t = threadIdx.x;
    const int m0 = blockIdx.x * 64, n0 = blockIdx.y * 64;
    const int tx = t & 15, ty = t >> 4;
    const int arow = t >> 2, acol4 = (t & 3) * 4;
    const int wrow = t >> 4, wcol4 = (t & 15) * 4;
    float c[4][4] = {};
    for (int k0 = 0; k0 < kD; k0 += 16) {
        const float4 av = *(const float4*)(A + (size_t)(m0 + arow) * kD + k0 + acol4);
        const float4 wv = *(const float4*)(W + (size_t)(k0 + wrow) * kD + n0 + wcol4);
        __syncthreads();
        As[acol4 + 0][arow] = av.x;
        As[acol4 + 1][arow] = av.y;
        As[acol4 + 2][arow] = av.z;
        As[acol4 + 3][arow] = av.w;
        *(float4*)&Ws[wrow][wcol4] = wv;
        __syncthreads();
        #pragma unroll
        for (int kk = 0; kk < 16; ++kk) {
            const float4 a = *(const float4*)&As[kk][ty * 4];
            const float4 wv2 = *(const float4*)&Ws[kk][tx * 4];
            c[0][0] += a.x * wv2.x; c[0][1] += a.x * wv2.y; c[0][2] += a.x * wv2.z; c[0][3] += a.x * wv2.w;
            c[1][0] += a.y * wv2.x; c[1][1] += a.y * wv2.y; c[1][2] += a.y * wv2.z; c[1][3] += a.y * wv2.w;
            c[2][0] += a.z * wv2.x; c[2][1] += a.z * wv2.y; c[2][2] += a.z * wv2.z; c[2][3] += a.z * wv2.w;
            c[3][0] += a.w * wv2.x; c[3][1] += a.w * wv2.y; c[3][2] += a.w * wv2.z; c[3][3] += a.w * wv2.w;
        }
    }
    const float4 bv = *(const float4*)(bias + n0 + tx * 4);
    #pragma unroll
    for (int i = 0; i < 4; ++i) {
        float4 o;
        o.x = c[i][0] + bv.x; o.y = c[i][1] + bv.y; o.z = c[i][2] + bv.z; o.w = c[i][3] + bv.w;
        *(float4*)(out + (size_t)(m0 + ty * 4 + i) * kD + n0 + tx * 4) = o;
    }
}

extern "C" void kernel_launch(void* const* d_in, const int* in_sizes, int n_in,
                              void* d_out, int out_size, void* d_ws, size_t ws_size,
                              hipStream_t stream) {
    const float* Q    = (const float*)d_in[0];
    const float* K    = (const float*)d_in[1];
    const float* V    = (const float*)d_in[2];
    const float* W    = (const float*)d_in[3];
    const float* bias = (const float*)d_in[4];
    float* out = (float*)d_out;

    if (ws_size >= kWsNeed) {
        char* ws = (char*)d_ws;
        _Float16* Kh = (_Float16*)(ws + kKhOff);
        _Float16* Vt = (_Float16*)(ws + kVtOff);
        _Float16* Ah = (_Float16*)(ws + kAhOff);
        _Float16* Wt = (_Float16*)(ws + kWtOff);

        conv_half<<<dim3((kB * kL * kD) / (256 * 8)), 256, 0, stream>>>(K, Kh);
        conv_vt<<<dim3(kB * kH * (kL / 64)), 256, 0, stream>>>(V, Vt);
        conv_wt<<<dim3(256), 256, 0, stream>>>(W, Wt);
        flash_kernel<<<dim3(kB * kH * (kL / 128)), 256, 0, stream>>>(Q, Kh, Vt, Ah);
        proj_half<<<dim3(kM / 128, kD / 64), 256, 0, stream>>>(Ah, Wt, bias, out);
    } else {
        float* A = (float*)d_ws;
        attn_kernel_f32<<<dim3(kB * kH * (kL / 4)), 256, 0, stream>>>(Q, K, V, A);
        proj_kernel_f32<<<dim3(kM / 64, kD / 64), 256, 0, stream>>>(A, W, bias, out);
    }
}